// Round 5
// baseline (820.269 us; speedup 1.0000x reference)
//
#include <hip/hip_runtime.h>
#include <math.h>

typedef float f4 __attribute__((ext_vector_type(4)));

// Problem constants: B=16, C=D=256, H=W=64 -> S=4096 spatial/batch, N=65536 rows, K=1024 codes.
#define GAP_TAU 0.05f

// ===========================================================================
// numpy-fp32 arithmetic replication helpers (baseline-SIMD SSE pairwise).
// numpy pairwise_sum FLOAT: n=256 -> P128(a)+P128(a+128); each 128-block:
// 8 vector accumulators x 4 lanes, 4 chunks of 32, vector tree-combine
// ((r0+r1)+(r2+r3))+((r4+r5)+(r6+r7)), then SSE3 hadd hsum (c0+c1)+(c2+c3).
// All ops strictly fp32 RN via __f*_rn intrinsics (never contracted to FMA).
// ===========================================================================
__device__ __forceinline__ float np_half128(const float* s) {
    float r[8][4];
    #pragma unroll
    for (int j = 0; j < 8; ++j)
        #pragma unroll
        for (int l = 0; l < 4; ++l) r[j][l] = s[j * 4 + l];
    #pragma unroll
    for (int m = 1; m < 4; ++m)
        #pragma unroll
        for (int j = 0; j < 8; ++j)
            #pragma unroll
            for (int l = 0; l < 4; ++l)
                r[j][l] = __fadd_rn(r[j][l], s[m * 32 + j * 4 + l]);
    float c[4];
    #pragma unroll
    for (int l = 0; l < 4; ++l) {
        float t01 = __fadd_rn(r[0][l], r[1][l]);
        float t23 = __fadd_rn(r[2][l], r[3][l]);
        float t45 = __fadd_rn(r[4][l], r[5][l]);
        float t67 = __fadd_rn(r[6][l], r[7][l]);
        c[l] = __fadd_rn(__fadd_rn(t01, t23), __fadd_rn(t45, t67));
    }
    return __fadd_rn(__fadd_rn(c[0], c[1]), __fadd_rn(c[2], c[3]));
}
__device__ __forceinline__ float np_sum256(const float* s) {
    return __fadd_rn(np_half128(s), np_half128(s + 128));
}

// ---------------------------------------------------------------------------
// K0: c2s[k] = (float)( sum_d codebook[k][d]^2 (fp64) - 256.0 )  [fast path]
// ---------------------------------------------------------------------------
__global__ __launch_bounds__(256) void k_c2(const float* __restrict__ cb,
                                            float* __restrict__ c2s) {
    int k = blockIdx.x * 256 + threadIdx.x;
    if (k >= 1024) return;
    const float* row = cb + (size_t)k * 256;
    double s = 0.0;
    for (int d = 0; d < 256; ++d) { double v = (double)row[d]; s += v * v; }
    c2s[k] = (float)(s - 256.0);
}

// ---------------------------------------------------------------------------
// K1: 1x1 conv (channel-mix GEMM) + fused L2 row-normalize (fast path).
// ---------------------------------------------------------------------------
__global__ __launch_bounds__(256) void k_conv(const float* __restrict__ x,
                                              const float* __restrict__ w,
                                              const float* __restrict__ bias,
                                              float* __restrict__ feat) {
    __shared__ f4 xs4[32 * 16];   // [kk][p/4]
    __shared__ f4 ws4[32 * 64];   // [kk][o/4]
    float* wsf = (float*)ws4;

    const int t  = threadIdx.x;
    const int og = t & 15;
    const int pg = t >> 4;
    const int b  = blockIdx.x >> 6;
    const int s0 = (blockIdx.x & 63) << 6;

    const f4* x4    = (const f4*)(x + ((size_t)b * 256) * 4096 + s0);
    const f4* w4row = (const f4*)(w + (size_t)t * 256);

    float acc[4][16];
    #pragma unroll
    for (int p = 0; p < 4; ++p)
        #pragma unroll
        for (int u = 0; u < 16; ++u) acc[p][u] = 0.f;

    for (int c0 = 0; c0 < 256; c0 += 32) {
        __syncthreads();
        #pragma unroll
        for (int j = 0; j < 2; ++j) {
            int lin = t + j * 256;
            int kk = lin >> 4, p4 = lin & 15;
            xs4[kk * 16 + p4] = x4[(size_t)(c0 + kk) * 1024 + p4];
        }
        {
            f4 wv[8];
            #pragma unroll
            for (int j = 0; j < 8; ++j) wv[j] = w4row[(c0 >> 2) + j];
            #pragma unroll
            for (int j = 0; j < 8; ++j)
                #pragma unroll
                for (int i = 0; i < 4; ++i)
                    wsf[(j * 4 + i) * 256 + t] = wv[j][i];
        }
        __syncthreads();
        #pragma unroll 8
        for (int kk = 0; kk < 32; ++kk) {
            f4 xv = xs4[kk * 16 + pg];
            f4 wv[4];
            wv[0] = ws4[kk * 64 + og];
            wv[1] = ws4[kk * 64 + og + 16];
            wv[2] = ws4[kk * 64 + og + 32];
            wv[3] = ws4[kk * 64 + og + 48];
            #pragma unroll
            for (int p = 0; p < 4; ++p)
                #pragma unroll
                for (int u = 0; u < 4; ++u)
                    #pragma unroll
                    for (int i = 0; i < 4; ++i)
                        acc[p][u * 4 + i] += xv[p] * wv[u][i];
        }
    }

    f4 bv[4];
    #pragma unroll
    for (int u = 0; u < 4; ++u) bv[u] = ((const f4*)bias)[og + 16 * u];

    const size_t n0 = (size_t)b * 4096 + s0;
    f4* feat4 = (f4*)feat;
    #pragma unroll
    for (int p = 0; p < 4; ++p) {
        f4 q[4];
        float n2 = 0.f;
        #pragma unroll
        for (int u = 0; u < 4; ++u)
            #pragma unroll
            for (int i = 0; i < 4; ++i) {
                float qv = acc[p][u * 4 + i] + bv[u][i];
                q[u][i] = qv;
                n2 += qv * qv;
            }
        #pragma unroll
        for (int m = 1; m <= 8; m <<= 1) n2 += __shfl_xor(n2, m, 64);
        float norm = fmaxf(sqrtf(n2), 1e-12f);
        float inv = 1.0f / norm;
        #pragma unroll
        for (int u = 0; u < 4; ++u) {
            f4 st;
            #pragma unroll
            for (int i = 0; i < 4; ++i) st[i] = q[u][i] * inv;
            feat4[(n0 + pg * 4 + p) * 64 + og + 16 * u] = st;
        }
    }
}

// ---------------------------------------------------------------------------
// K2: distance argmin (fast fp32 path) + near-tie flagging (gap < GAP_TAU).
// ---------------------------------------------------------------------------
__global__ __launch_bounds__(256) void k_dist(const float* __restrict__ feat,
                                              const float* __restrict__ cb,
                                              const float* __restrict__ c2s,
                                              int* __restrict__ idxout,
                                              int* __restrict__ flagcnt,
                                              int* __restrict__ flaglist) {
    __shared__ f4 fs4[256 * 8];   // [d][pblock^swz]
    __shared__ f4 es4[64 * 32];   // [d_local][cblock^swz]

    const int t  = threadIdx.x;
    const int og = t & 31;
    const int pg = t >> 5;
    const size_t n0 = (size_t)blockIdx.x * 32;

    const f4* feat4 = (const f4*)feat;
    const f4* cb4   = (const f4*)cb;

    #pragma unroll
    for (int j = 0; j < 2; ++j) {
        int lin = t + j * 256;
        int rg = lin >> 6, d4 = lin & 63;
        f4 a0 = feat4[(n0 + rg * 4 + 0) * 64 + d4];
        f4 a1 = feat4[(n0 + rg * 4 + 1) * 64 + d4];
        f4 a2 = feat4[(n0 + rg * 4 + 2) * 64 + d4];
        f4 a3 = feat4[(n0 + rg * 4 + 3) * 64 + d4];
        int cblk = rg ^ (d4 & 7);
        #pragma unroll
        for (int i = 0; i < 4; ++i) {
            f4 wv = {a0[i], a1[i], a2[i], a3[i]};
            fs4[(4 * d4 + i) * 8 + cblk] = wv;
        }
    }

    float best[4], best2[4]; int bidx[4];
    #pragma unroll
    for (int p = 0; p < 4; ++p) { best[p] = 3.4e38f; best2[p] = 3.4e38f; bidx[p] = 0; }

    for (int kc = 0; kc < 8; ++kc) {
        const int k0 = kc * 128;
        float acc[4][4];
        #pragma unroll
        for (int p = 0; p < 4; ++p)
            #pragma unroll
            for (int c = 0; c < 4; ++c) acc[p][c] = 0.f;

        for (int dc = 0; dc < 4; ++dc) {
            __syncthreads();
            #pragma unroll
            for (int j = 0; j < 2; ++j) {
                int lin = t + j * 256;
                int d4 = lin & 15, rg = lin >> 4;
                f4 a0 = cb4[(size_t)(k0 + rg * 4 + 0) * 64 + dc * 16 + d4];
                f4 a1 = cb4[(size_t)(k0 + rg * 4 + 1) * 64 + dc * 16 + d4];
                f4 a2 = cb4[(size_t)(k0 + rg * 4 + 2) * 64 + dc * 16 + d4];
                f4 a3 = cb4[(size_t)(k0 + rg * 4 + 3) * 64 + dc * 16 + d4];
                int cblk = rg ^ (d4 & 7);
                #pragma unroll
                for (int i = 0; i < 4; ++i) {
                    f4 wv = {a0[i], a1[i], a2[i], a3[i]};
                    es4[(4 * d4 + i) * 32 + cblk] = wv;
                }
            }
            __syncthreads();
            #pragma unroll
            for (int kk4 = 0; kk4 < 16; ++kk4) {
                const int v = kk4 & 7;
                const f4* fp = fs4 + (dc * 64 + kk4 * 4) * 8 + (pg ^ v);
                const f4* ep = es4 + (kk4 * 4) * 32 + (og ^ v);
                #pragma unroll
                for (int i = 0; i < 4; ++i) {
                    f4 fv = fp[i * 8];
                    f4 ev = ep[i * 32];
                    #pragma unroll
                    for (int p = 0; p < 4; ++p)
                        #pragma unroll
                        for (int c = 0; c < 4; ++c)
                            acc[p][c] += fv[p] * ev[c];
                }
            }
        }
        f4 c2v = ((const f4*)c2s)[(k0 >> 2) + og];
        #pragma unroll
        for (int c = 0; c < 4; ++c) {
            int code = k0 + og * 4 + c;
            #pragma unroll
            for (int p = 0; p < 4; ++p) {
                float s = c2v[c] - 2.0f * acc[p][c];
                if (s < best[p]) { best2[p] = best[p]; best[p] = s; bidx[p] = code; }
                else if (s < best2[p]) { best2[p] = s; }
            }
        }
    }

    #pragma unroll
    for (int m = 1; m <= 16; m <<= 1) {
        #pragma unroll
        for (int p = 0; p < 4; ++p) {
            float ov  = __shfl_xor(best[p],  m, 64);
            int   oi  = __shfl_xor(bidx[p],  m, 64);
            float ov2 = __shfl_xor(best2[p], m, 64);
            bool owin = (ov < best[p]) || (ov == best[p] && oi < bidx[p]);
            float loser = owin ? best[p] : ov;
            best2[p] = fminf(fminf(best2[p], ov2), loser);
            if (owin) { best[p] = ov; bidx[p] = oi; }
        }
    }
    if (og == 0) {
        #pragma unroll
        for (int p = 0; p < 4; ++p) {
            int n = (int)n0 + pg * 4 + p;
            idxout[n] = bidx[p];
            if (best2[p] - best[p] < GAP_TAU) {
                int slot = atomicAdd(flagcnt, 1);
                if (slot < 65536) flaglist[slot] = n;
            }
        }
    }
}

// ---------------------------------------------------------------------------
// K2b: refine flagged rows by REPLICATING the numpy-fp32 reference pipeline:
//   flat[o]  = fl32-einsum(x,w) + bias    (4-lane SSE dot emu, mul+add, hadd)
//   norm     = sqrtf(np_pairwise(flat^2)); fn = flat / max(norm,1e-12)
//   t1       = np_pairwise(fn^2)
//   e2[k]    = np_pairwise(e^2)           (bit-replicated numpy sum order)
//   G[k]     = fl32( exact dot(2*fn, e) ) (sgemm order unknowable; +-1e-6)
//   d2       = fl32( fl32(t1 - G) + e2 ); argmin first-min  == np.argmin
// ---------------------------------------------------------------------------
__global__ __launch_bounds__(256) void k_refine(const float* __restrict__ x,
                                                const float* __restrict__ w,
                                                const float* __restrict__ bias,
                                                const float* __restrict__ cb,
                                                const int* __restrict__ flaglist,
                                                const int* __restrict__ flagcnt,
                                                int* __restrict__ idxout) {
    __shared__ float xs[256];
    __shared__ float flat[256];
    __shared__ float fn[256];
    __shared__ float sq[256];
    __shared__ float sv[256];
    __shared__ int   si[256];
    __shared__ float bc[2];
    const int t = threadIdx.x;
    int cnt = *flagcnt;
    if (cnt > 65536) cnt = 65536;

    for (int r = blockIdx.x; r < cnt; r += gridDim.x) {
        const int n = flaglist[r];
        const int b = n >> 12, s = n & 4095;
        xs[t] = x[((size_t)b * 256 + t) * 4096 + s];
        __syncthreads();

        // einsum emu: q[o=t] = SSE 4-lane dot over c, then + bias (fp32 RN)
        {
            const f4* xv4 = (const f4*)xs;
            const f4* wv4 = (const f4*)(w + (size_t)t * 256);
            float a0 = 0.f, a1 = 0.f, a2 = 0.f, a3 = 0.f;
            for (int c4 = 0; c4 < 64; ++c4) {
                f4 xv = xv4[c4];
                f4 wv = wv4[c4];
                a0 = __fadd_rn(a0, __fmul_rn(xv[0], wv[0]));
                a1 = __fadd_rn(a1, __fmul_rn(xv[1], wv[1]));
                a2 = __fadd_rn(a2, __fmul_rn(xv[2], wv[2]));
                a3 = __fadd_rn(a3, __fmul_rn(xv[3], wv[3]));
            }
            float q = __fadd_rn(__fadd_rn(a0, a1), __fadd_rn(a2, a3));
            flat[t] = __fadd_rn(q, bias[t]);
        }
        sq[t] = __fmul_rn(flat[t], flat[t]);
        __syncthreads();
        if (t == 0) bc[0] = fmaxf(__fsqrt_rn(np_sum256(sq)), 1e-12f);
        __syncthreads();
        fn[t] = __fdiv_rn(flat[t], bc[0]);
        __syncthreads();
        sq[t] = __fmul_rn(fn[t], fn[t]);
        __syncthreads();
        if (t == 0) bc[1] = np_sum256(sq);
        __syncthreads();
        const float t1f = bc[1];

        float best = 3.4e38f; int bi = 0x7fffffff;
        #pragma unroll 1
        for (int kq = 0; kq < 4; ++kq) {
            int k = kq * 256 + t;
            const f4* e4 = (const f4*)(cb + (size_t)k * 256);
            double dot = 0.0;
            float hres[2];
            #pragma unroll 1
            for (int h = 0; h < 2; ++h) {
                float rr[8][4];
                #pragma unroll
                for (int j = 0; j < 8; ++j)
                    #pragma unroll
                    for (int l = 0; l < 4; ++l) rr[j][l] = 0.f;
                #pragma unroll 1
                for (int m = 0; m < 4; ++m) {
                    #pragma unroll
                    for (int j = 0; j < 8; ++j) {
                        f4 v = e4[h * 32 + m * 8 + j];
                        #pragma unroll
                        for (int l = 0; l < 4; ++l) {
                            dot += (double)fn[h * 128 + m * 32 + j * 4 + l] * (double)v[l];
                            rr[j][l] = __fadd_rn(rr[j][l], __fmul_rn(v[l], v[l]));
                        }
                    }
                }
                float c[4];
                #pragma unroll
                for (int l = 0; l < 4; ++l) {
                    float t01 = __fadd_rn(rr[0][l], rr[1][l]);
                    float t23 = __fadd_rn(rr[2][l], rr[3][l]);
                    float t45 = __fadd_rn(rr[4][l], rr[5][l]);
                    float t67 = __fadd_rn(rr[6][l], rr[7][l]);
                    c[l] = __fadd_rn(__fadd_rn(t01, t23), __fadd_rn(t45, t67));
                }
                hres[h] = __fadd_rn(__fadd_rn(c[0], c[1]), __fadd_rn(c[2], c[3]));
            }
            float e2f = __fadd_rn(hres[0], hres[1]);
            float gf  = (float)(2.0 * dot);
            float d2  = __fadd_rn(__fsub_rn(t1f, gf), e2f);
            if (d2 < best) { best = d2; bi = k; }
        }
        sv[t] = best; si[t] = bi;
        __syncthreads();
        for (int off = 128; off > 0; off >>= 1) {
            if (t < off) {
                if (sv[t + off] < sv[t] || (sv[t + off] == sv[t] && si[t + off] < si[t])) {
                    sv[t] = sv[t + off]; si[t] = si[t + off];
                }
            }
            __syncthreads();
        }
        if (t == 0) idxout[n] = si[0];
        __syncthreads();
    }
}

// ---------------------------------------------------------------------------
// K3: gather + NHWC->NCHW write.
// ---------------------------------------------------------------------------
__global__ __launch_bounds__(256) void k_gather(const int* __restrict__ idx,
                                                const float* __restrict__ cb,
                                                float* __restrict__ out) {
    const int t = threadIdx.x;
    const int b = blockIdx.x >> 4;
    const int s = ((blockIdx.x & 15) << 8) + t;
    const int n = b * 4096 + s;
    const int k = idx[n];
    const f4* row = (const f4*)(cb + (size_t)k * 256);
    float* ob = out + (size_t)b * 256 * 4096 + s;
    #pragma unroll 8
    for (int d4 = 0; d4 < 64; ++d4) {
        f4 v = row[d4];
        ob[(size_t)(d4 * 4 + 0) * 4096] = v[0];
        ob[(size_t)(d4 * 4 + 1) * 4096] = v[1];
        ob[(size_t)(d4 * 4 + 2) * 4096] = v[2];
        ob[(size_t)(d4 * 4 + 3) * 4096] = v[3];
    }
}

// ---------------------------------------------------------------------------
extern "C" void kernel_launch(void* const* d_in, const int* in_sizes, int n_in,
                              void* d_out, int out_size, void* d_ws, size_t ws_size,
                              hipStream_t stream) {
    const float* x    = (const float*)d_in[0];
    const float* w    = (const float*)d_in[1];
    const float* bias = (const float*)d_in[2];
    const float* cb   = (const float*)d_in[3];
    float* out = (float*)d_out;

    char* ws = (char*)d_ws;
    float* feat   = (float*)ws;                              // 67108864 B
    int*   idx    = (int*)(ws + 67108864);                   //   262144 B
    float* c2s    = (float*)(ws + 67108864 + 262144);        //     4096 B
    int*   fcnt   = (int*)(ws + 67108864 + 262144 + 4096);   //      256 B (pad)
    int*   flist  = (int*)(ws + 67108864 + 262144 + 4096 + 256); // 262144 B

    hipMemsetAsync(fcnt, 0, 4, stream);
    k_c2    <<<4,    256, 0, stream>>>(cb, c2s);
    k_conv  <<<1024, 256, 0, stream>>>(x, w, bias, feat);
    k_dist  <<<2048, 256, 0, stream>>>(feat, cb, c2s, idx, fcnt, flist);
    k_refine<<<256,  256, 0, stream>>>(x, w, bias, cb, flist, fcnt, idx);
    k_gather<<<256,  256, 0, stream>>>(idx, cb, out);
}

// Round 7
// 616.574 us; speedup vs baseline: 1.3304x; 1.3304x over previous
//
#include <hip/hip_runtime.h>
#include <math.h>

typedef float f4 __attribute__((ext_vector_type(4)));
typedef __attribute__((ext_vector_type(8)))  __bf16 bf16x8;
typedef __attribute__((ext_vector_type(16))) float  f32x16;
typedef __attribute__((ext_vector_type(4)))  unsigned short us4;

// Problem constants: B=16, C=D=256, H=W=64 -> S=4096 spatial/batch, N=65536 rows, K=1024 codes.
#define GAP_TAU 0.05f

// float -> bf16 round-to-nearest-even (no NaN handling needed here)
__device__ __forceinline__ unsigned short f2bf(float f) {
    unsigned int u = __float_as_uint(f);
    return (unsigned short)((u + 0x7fffu + ((u >> 16) & 1u)) >> 16);
}

// ===========================================================================
// numpy-fp32 pairwise-sum replication helpers (baseline-SIMD SSE order).
// ===========================================================================
__device__ __forceinline__ float np_half128(const float* s) {
    float r[8][4];
    #pragma unroll
    for (int j = 0; j < 8; ++j)
        #pragma unroll
        for (int l = 0; l < 4; ++l) r[j][l] = s[j * 4 + l];
    #pragma unroll
    for (int m = 1; m < 4; ++m)
        #pragma unroll
        for (int j = 0; j < 8; ++j)
            #pragma unroll
            for (int l = 0; l < 4; ++l)
                r[j][l] = __fadd_rn(r[j][l], s[m * 32 + j * 4 + l]);
    float c[4];
    #pragma unroll
    for (int l = 0; l < 4; ++l) {
        float t01 = __fadd_rn(r[0][l], r[1][l]);
        float t23 = __fadd_rn(r[2][l], r[3][l]);
        float t45 = __fadd_rn(r[4][l], r[5][l]);
        float t67 = __fadd_rn(r[6][l], r[7][l]);
        c[l] = __fadd_rn(__fadd_rn(t01, t23), __fadd_rn(t45, t67));
    }
    return __fadd_rn(__fadd_rn(c[0], c[1]), __fadd_rn(c[2], c[3]));
}
__device__ __forceinline__ float np_sum256(const float* s) {
    return __fadd_rn(np_half128(s), np_half128(s + 128));
}

// ---------------------------------------------------------------------------
// K0: c2s[k] = (float)( sum_d codebook[k][d]^2 (fp64) - 256.0 )  [fast path]
// ---------------------------------------------------------------------------
__global__ __launch_bounds__(256) void k_c2(const float* __restrict__ cb,
                                            float* __restrict__ c2s) {
    int k = blockIdx.x * 256 + threadIdx.x;
    if (k >= 1024) return;
    const float* row = cb + (size_t)k * 256;
    double s = 0.0;
    for (int d = 0; d < 256; ++d) { double v = (double)row[d]; s += v * v; }
    c2s[k] = (float)(s - 256.0);
}

// ---------------------------------------------------------------------------
// K0b: split codebook into bf16 hi/lo planes (e = eh + el + O(2^-18 e)).
// ---------------------------------------------------------------------------
__global__ __launch_bounds__(256) void k_pack(const float* __restrict__ cb,
                                              unsigned short* __restrict__ eh,
                                              unsigned short* __restrict__ el) {
    int i = blockIdx.x * 256 + threadIdx.x;   // grid 1024 -> 262144 elems
    float v = cb[i];
    unsigned short h = f2bf(v);
    float hf = __uint_as_float((unsigned int)h << 16);
    eh[i] = h;
    el[i] = f2bf(v - hf);
}

// ---------------------------------------------------------------------------
// K1: 1x1 conv (channel-mix GEMM) + fused L2 row-normalize.
// Emits normalized features as bf16 hi/lo planes [n][256].
// ---------------------------------------------------------------------------
__global__ __launch_bounds__(256) void k_conv(const float* __restrict__ x,
                                              const float* __restrict__ w,
                                              const float* __restrict__ bias,
                                              unsigned short* __restrict__ fh,
                                              unsigned short* __restrict__ fl) {
    __shared__ f4 xs4[32 * 16];   // [kk][p/4]
    __shared__ f4 ws4[32 * 64];   // [kk][o/4]
    float* wsf = (float*)ws4;

    const int t  = threadIdx.x;
    const int og = t & 15;
    const int pg = t >> 4;
    const int b  = blockIdx.x >> 6;
    const int s0 = (blockIdx.x & 63) << 6;

    const f4* x4    = (const f4*)(x + ((size_t)b * 256) * 4096 + s0);
    const f4* w4row = (const f4*)(w + (size_t)t * 256);

    float acc[4][16];
    #pragma unroll
    for (int p = 0; p < 4; ++p)
        #pragma unroll
        for (int u = 0; u < 16; ++u) acc[p][u] = 0.f;

    for (int c0 = 0; c0 < 256; c0 += 32) {
        __syncthreads();
        #pragma unroll
        for (int j = 0; j < 2; ++j) {
            int lin = t + j * 256;
            int kk = lin >> 4, p4 = lin & 15;
            xs4[kk * 16 + p4] = x4[(size_t)(c0 + kk) * 1024 + p4];
        }
        {
            f4 wv[8];
            #pragma unroll
            for (int j = 0; j < 8; ++j) wv[j] = w4row[(c0 >> 2) + j];
            #pragma unroll
            for (int j = 0; j < 8; ++j)
                #pragma unroll
                for (int i = 0; i < 4; ++i)
                    wsf[(j * 4 + i) * 256 + t] = wv[j][i];
        }
        __syncthreads();
        #pragma unroll 8
        for (int kk = 0; kk < 32; ++kk) {
            f4 xv = xs4[kk * 16 + pg];
            f4 wv[4];
            wv[0] = ws4[kk * 64 + og];
            wv[1] = ws4[kk * 64 + og + 16];
            wv[2] = ws4[kk * 64 + og + 32];
            wv[3] = ws4[kk * 64 + og + 48];
            #pragma unroll
            for (int p = 0; p < 4; ++p)
                #pragma unroll
                for (int u = 0; u < 4; ++u)
                    #pragma unroll
                    for (int i = 0; i < 4; ++i)
                        acc[p][u * 4 + i] += xv[p] * wv[u][i];
        }
    }

    f4 bv[4];
    #pragma unroll
    for (int u = 0; u < 4; ++u) bv[u] = ((const f4*)bias)[og + 16 * u];

    const size_t n0 = (size_t)b * 4096 + s0;
    us4* fh4 = (us4*)fh;
    us4* fl4 = (us4*)fl;
    #pragma unroll
    for (int p = 0; p < 4; ++p) {
        f4 q[4];
        float n2 = 0.f;
        #pragma unroll
        for (int u = 0; u < 4; ++u)
            #pragma unroll
            for (int i = 0; i < 4; ++i) {
                float qv = acc[p][u * 4 + i] + bv[u][i];
                q[u][i] = qv;
                n2 += qv * qv;
            }
        #pragma unroll
        for (int m = 1; m <= 8; m <<= 1) n2 += __shfl_xor(n2, m, 64);
        float norm = fmaxf(sqrtf(n2), 1e-12f);
        float inv = 1.0f / norm;
        #pragma unroll
        for (int u = 0; u < 4; ++u) {
            us4 sh, sl;
            #pragma unroll
            for (int i = 0; i < 4; ++i) {
                float v = q[u][i] * inv;
                unsigned short h = f2bf(v);
                sh[i] = h;
                sl[i] = f2bf(v - __uint_as_float((unsigned int)h << 16));
            }
            size_t o8 = (n0 + pg * 4 + p) * 64 + og + 16 * u;
            fh4[o8] = sh;
            fl4[o8] = sl;
        }
    }
}

// ---------------------------------------------------------------------------
// K2: distance argmin via bf16-split MFMA (mfma_f32_32x32x16_bf16).
// Block: 512 thr / 8 waves; tile = 64 pos x 1024 codes.
// F hi/lo staged in LDS (XOR-swizzled 16B chunks); E hi/lo planes read from
// global (L2-resident, each code's B-frags read by exactly one wave).
// dot ~ fh*eh + fh*el + fl*eh (error ~2e-5 << GAP_TAU). Score = c2s - 2*dot.
// Top-2 tracked per lane over ct, merged cross-lane then cross-wave.
// ---------------------------------------------------------------------------
__global__ __launch_bounds__(512) void k_dist(const unsigned short* __restrict__ fh_g,
                                              const unsigned short* __restrict__ fl_g,
                                              const unsigned short* __restrict__ eh_g,
                                              const unsigned short* __restrict__ el_g,
                                              const float* __restrict__ c2s,
                                              int* __restrict__ idxout,
                                              int* __restrict__ flagcnt,
                                              int* __restrict__ flaglist) {
    __shared__ f4 fhs[64 * 32];   // [pos][chunk^swz] 16B units (32 KB)
    __shared__ f4 fls[64 * 32];   // 32 KB
    __shared__ float sb[8][64];
    __shared__ float sb2[8][64];
    __shared__ int   sbi[8][64];

    const int t  = threadIdx.x;
    const int w  = t >> 6;        // wave 0..7
    const int l  = t & 63;
    const int n0 = blockIdx.x * 64;

    // stage F planes: 64 pos x 32 chunks each, swizzle chunk ^= pos&7
    const f4* fh4 = (const f4*)fh_g + (size_t)n0 * 32;
    const f4* fl4 = (const f4*)fl_g + (size_t)n0 * 32;
    #pragma unroll
    for (int j = 0; j < 4; ++j) {
        int lin = j * 512 + t;
        int pos = lin >> 5, c = lin & 31;
        int sw = pos * 32 + (c ^ (pos & 7));
        fhs[sw] = fh4[lin];
        fls[sw] = fl4[lin];
    }
    __syncthreads();

    f32x16 acc[4][2];
    #pragma unroll
    for (int ct = 0; ct < 4; ++ct)
        #pragma unroll
        for (int pt = 0; pt < 2; ++pt)
            #pragma unroll
            for (int r = 0; r < 16; ++r) acc[ct][pt][r] = 0.f;

    const int col = l & 31;       // A row / B col / D col
    const int g   = l >> 5;       // k-group
    const int sw7 = col & 7;      // swizzle key (same for pos and pos+32)
    const f4* ehp = (const f4*)eh_g;
    const f4* elp = (const f4*)el_g;

    for (int kc = 0; kc < 16; ++kc) {
        int chunk = kc * 2 + g;
        int swc = chunk ^ sw7;
        bf16x8 ah0 = __builtin_bit_cast(bf16x8, fhs[col * 32 + swc]);
        bf16x8 al0 = __builtin_bit_cast(bf16x8, fls[col * 32 + swc]);
        bf16x8 ah1 = __builtin_bit_cast(bf16x8, fhs[(col + 32) * 32 + swc]);
        bf16x8 al1 = __builtin_bit_cast(bf16x8, fls[(col + 32) * 32 + swc]);
        #pragma unroll
        for (int ct = 0; ct < 4; ++ct) {
            int code = w * 128 + ct * 32 + col;
            bf16x8 bh = __builtin_bit_cast(bf16x8, ehp[code * 32 + chunk]);
            bf16x8 bl = __builtin_bit_cast(bf16x8, elp[code * 32 + chunk]);
            acc[ct][0] = __builtin_amdgcn_mfma_f32_32x32x16_bf16(ah0, bh, acc[ct][0], 0, 0, 0);
            acc[ct][0] = __builtin_amdgcn_mfma_f32_32x32x16_bf16(ah0, bl, acc[ct][0], 0, 0, 0);
            acc[ct][0] = __builtin_amdgcn_mfma_f32_32x32x16_bf16(al0, bh, acc[ct][0], 0, 0, 0);
            acc[ct][1] = __builtin_amdgcn_mfma_f32_32x32x16_bf16(ah1, bh, acc[ct][1], 0, 0, 0);
            acc[ct][1] = __builtin_amdgcn_mfma_f32_32x32x16_bf16(ah1, bl, acc[ct][1], 0, 0, 0);
            acc[ct][1] = __builtin_amdgcn_mfma_f32_32x32x16_bf16(al1, bh, acc[ct][1], 0, 0, 0);
        }
    }

    // scores + top-2 argmin. D layout: col = l&31, row = (r&3)+8*(r>>2)+4*g.
    #pragma unroll
    for (int pt = 0; pt < 2; ++pt) {
        float best[16], best2[16]; int bidx[16];
        #pragma unroll
        for (int r = 0; r < 16; ++r) { best[r] = 3.4e38f; best2[r] = 3.4e38f; bidx[r] = 0; }
        #pragma unroll
        for (int ct = 0; ct < 4; ++ct) {
            int code = w * 128 + ct * 32 + col;
            float c2 = c2s[code];
            #pragma unroll
            for (int r = 0; r < 16; ++r) {
                float s = fmaf(-2.0f, acc[ct][pt][r], c2);
                if (s < best[r]) { best2[r] = best[r]; best[r] = s; bidx[r] = code; }
                else if (s < best2[r]) { best2[r] = s; }
            }
        }
        #pragma unroll
        for (int m = 1; m <= 16; m <<= 1) {
            #pragma unroll
            for (int r = 0; r < 16; ++r) {
                float ov  = __shfl_xor(best[r],  m, 64);
                int   oi  = __shfl_xor(bidx[r],  m, 64);
                float ov2 = __shfl_xor(best2[r], m, 64);
                bool owin = (ov < best[r]) || (ov == best[r] && oi < bidx[r]);
                float loser = owin ? best[r] : ov;
                best2[r] = fminf(fminf(best2[r], ov2), loser);
                if (owin) { best[r] = ov; bidx[r] = oi; }
            }
        }
        if (col == 0) {
            #pragma unroll
            for (int r = 0; r < 16; ++r) {
                int pos = pt * 32 + (r & 3) + 8 * (r >> 2) + 4 * g;
                sb[w][pos] = best[r]; sb2[w][pos] = best2[r]; sbi[w][pos] = bidx[r];
            }
        }
    }
    __syncthreads();

    if (t < 64) {
        float b = 3.4e38f, b2 = 3.4e38f; int bi = 0;
        #pragma unroll
        for (int ww = 0; ww < 8; ++ww) {
            float ov = sb[ww][t]; int oi = sbi[ww][t]; float ov2 = sb2[ww][t];
            bool owin = (ov < b) || (ov == b && oi < bi);
            float loser = owin ? b : ov;
            b2 = fminf(fminf(b2, ov2), loser);
            if (owin) { b = ov; bi = oi; }
        }
        int n = n0 + t;
        idxout[n] = bi;
        if (b2 - b < GAP_TAU) {
            int slot = atomicAdd(flagcnt, 1);
            if (slot < 65536) flaglist[slot] = n;
        }
    }
}

// ---------------------------------------------------------------------------
// K2b: refine flagged rows, replicating the numpy-fp32 reference pipeline.
// (unchanged from the passing round)
// ---------------------------------------------------------------------------
__global__ __launch_bounds__(256) void k_refine(const float* __restrict__ x,
                                                const float* __restrict__ w,
                                                const float* __restrict__ bias,
                                                const float* __restrict__ cb,
                                                const int* __restrict__ flaglist,
                                                const int* __restrict__ flagcnt,
                                                int* __restrict__ idxout) {
    __shared__ float xs[256];
    __shared__ float flat[256];
    __shared__ float fn[256];
    __shared__ float sq[256];
    __shared__ float sv[256];
    __shared__ int   si[256];
    __shared__ float bc[2];
    const int t = threadIdx.x;
    int cnt = *flagcnt;
    if (cnt > 65536) cnt = 65536;

    for (int r = blockIdx.x; r < cnt; r += gridDim.x) {
        const int n = flaglist[r];
        const int b = n >> 12, s = n & 4095;
        xs[t] = x[((size_t)b * 256 + t) * 4096 + s];
        __syncthreads();
        {
            const f4* xv4 = (const f4*)xs;
            const f4* wv4 = (const f4*)(w + (size_t)t * 256);
            float a0 = 0.f, a1 = 0.f, a2 = 0.f, a3 = 0.f;
            for (int c4 = 0; c4 < 64; ++c4) {
                f4 xv = xv4[c4];
                f4 wv = wv4[c4];
                a0 = __fadd_rn(a0, __fmul_rn(xv[0], wv[0]));
                a1 = __fadd_rn(a1, __fmul_rn(xv[1], wv[1]));
                a2 = __fadd_rn(a2, __fmul_rn(xv[2], wv[2]));
                a3 = __fadd_rn(a3, __fmul_rn(xv[3], wv[3]));
            }
            float q = __fadd_rn(__fadd_rn(a0, a1), __fadd_rn(a2, a3));
            flat[t] = __fadd_rn(q, bias[t]);
        }
        sq[t] = __fmul_rn(flat[t], flat[t]);
        __syncthreads();
        if (t == 0) bc[0] = fmaxf(__fsqrt_rn(np_sum256(sq)), 1e-12f);
        __syncthreads();
        fn[t] = __fdiv_rn(flat[t], bc[0]);
        __syncthreads();
        sq[t] = __fmul_rn(fn[t], fn[t]);
        __syncthreads();
        if (t == 0) bc[1] = np_sum256(sq);
        __syncthreads();
        const float t1f = bc[1];

        float best = 3.4e38f; int bi = 0x7fffffff;
        #pragma unroll 1
        for (int kq = 0; kq < 4; ++kq) {
            int k = kq * 256 + t;
            const f4* e4 = (const f4*)(cb + (size_t)k * 256);
            double dot = 0.0;
            float hres[2];
            #pragma unroll 1
            for (int h = 0; h < 2; ++h) {
                float rr[8][4];
                #pragma unroll
                for (int j = 0; j < 8; ++j)
                    #pragma unroll
                    for (int l = 0; l < 4; ++l) rr[j][l] = 0.f;
                #pragma unroll 1
                for (int m = 0; m < 4; ++m) {
                    #pragma unroll
                    for (int j = 0; j < 8; ++j) {
                        f4 v = e4[h * 32 + m * 8 + j];
                        #pragma unroll
                        for (int l = 0; l < 4; ++l) {
                            dot += (double)fn[h * 128 + m * 32 + j * 4 + l] * (double)v[l];
                            rr[j][l] = __fadd_rn(rr[j][l], __fmul_rn(v[l], v[l]));
                        }
                    }
                }
                float c[4];
                #pragma unroll
                for (int l = 0; l < 4; ++l) {
                    float t01 = __fadd_rn(rr[0][l], rr[1][l]);
                    float t23 = __fadd_rn(rr[2][l], rr[3][l]);
                    float t45 = __fadd_rn(rr[4][l], rr[5][l]);
                    float t67 = __fadd_rn(rr[6][l], rr[7][l]);
                    c[l] = __fadd_rn(__fadd_rn(t01, t23), __fadd_rn(t45, t67));
                }
                hres[h] = __fadd_rn(__fadd_rn(c[0], c[1]), __fadd_rn(c[2], c[3]));
            }
            float e2f = __fadd_rn(hres[0], hres[1]);
            float gf  = (float)(2.0 * dot);
            float d2  = __fadd_rn(__fsub_rn(t1f, gf), e2f);
            if (d2 < best) { best = d2; bi = k; }
        }
        sv[t] = best; si[t] = bi;
        __syncthreads();
        for (int off = 128; off > 0; off >>= 1) {
            if (t < off) {
                if (sv[t + off] < sv[t] || (sv[t + off] == sv[t] && si[t + off] < si[t])) {
                    sv[t] = sv[t + off]; si[t] = si[t + off];
                }
            }
            __syncthreads();
        }
        if (t == 0) idxout[n] = si[0];
        __syncthreads();
    }
}

// ---------------------------------------------------------------------------
// K3: gather + NHWC->NCHW write.
// ---------------------------------------------------------------------------
__global__ __launch_bounds__(256) void k_gather(const int* __restrict__ idx,
                                                const float* __restrict__ cb,
                                                float* __restrict__ out) {
    const int t = threadIdx.x;
    const int b = blockIdx.x >> 4;
    const int s = ((blockIdx.x & 15) << 8) + t;
    const int n = b * 4096 + s;
    const int k = idx[n];
    const f4* row = (const f4*)(cb + (size_t)k * 256);
    float* ob = out + (size_t)b * 256 * 4096 + s;
    #pragma unroll 8
    for (int d4 = 0; d4 < 64; ++d4) {
        f4 v = row[d4];
        ob[(size_t)(d4 * 4 + 0) * 4096] = v[0];
        ob[(size_t)(d4 * 4 + 1) * 4096] = v[1];
        ob[(size_t)(d4 * 4 + 2) * 4096] = v[2];
        ob[(size_t)(d4 * 4 + 3) * 4096] = v[3];
    }
}

// ---------------------------------------------------------------------------
extern "C" void kernel_launch(void* const* d_in, const int* in_sizes, int n_in,
                              void* d_out, int out_size, void* d_ws, size_t ws_size,
                              hipStream_t stream) {
    const float* x    = (const float*)d_in[0];
    const float* w    = (const float*)d_in[1];
    const float* bias = (const float*)d_in[2];
    const float* cb   = (const float*)d_in[3];
    float* out = (float*)d_out;

    char* ws = (char*)d_ws;
    unsigned short* fh    = (unsigned short*)ws;                  // 33554432 B
    unsigned short* fl    = (unsigned short*)(ws + 33554432);     // 33554432 B
    int*            idx   = (int*)(ws + 67108864);                //   262144 B
    float*          c2s   = (float*)(ws + 67371008);              //     4096 B
    int*            fcnt  = (int*)(ws + 67375104);                //      256 B
    int*            flist = (int*)(ws + 67375360);                //   262144 B
    unsigned short* eh    = (unsigned short*)(ws + 67637504);     //   524288 B
    unsigned short* el    = (unsigned short*)(ws + 68161792);     //   524288 B

    hipMemsetAsync(fcnt, 0, 4, stream);
    k_c2    <<<4,    256, 0, stream>>>(cb, c2s);
    k_pack  <<<1024, 256, 0, stream>>>(cb, eh, el);
    k_conv  <<<1024, 256, 0, stream>>>(x, w, bias, fh, fl);
    k_dist  <<<1024, 512, 0, stream>>>(fh, fl, eh, el, c2s, idx, fcnt, flist);
    k_refine<<<256,  256, 0, stream>>>(x, w, bias, cb, flist, fcnt, idx);
    k_gather<<<256,  256, 0, stream>>>(idx, cb, out);
}